// Round 1
// baseline (62311.743 us; speedup 1.0000x reference)
//
#include <hip/hip_runtime.h>
#include <math.h>

// LatentNeuralOperator: sequential scan over T=256, parallel over B=2048.
// One workgroup (256 thr = 4 waves) per batch element; token state [32][64]
// lives in LDS for the whole scan. fp32 baseline (no fp32 MFMA on CDNA4).
//
// Thread mappings (lane = tid&63, wv = tid>>6):
//  - LN stats: 8 lanes per row (row = tid>>3), shfl_xor reduce over masks 1,2,4
//  - token mm1 (hidden[th][w]): lane=w, wave handles 16 th; weights uniform->s_load
//  - token mm2 (out[w][ld]):    lane=w, wave handles 8 ld;  weights uniform->s_load
//  - chan  mm1 (h2[ld][ch]):    thread = (ch=lane, ch+64) x 8 ld; ciW coalesced vec loads
//  - chan  mm2 (out[ld][w]):    lane=w, wave handles 8 ld; coW coalesced vec loads
// LDS rows padded (+4) => stride-1 row access conflict-free, float4-aligned.

namespace {
constexpr int Bb = 2048, Tt = 256, LD = 32, PD = 8, W = 64, NL = 3, TH = 64, CH = 128;
constexpr int WP  = W + 4;    // 68 floats/row, 272B (16B aligned)
constexpr int CHP = CH + 4;   // 132 floats/row, 528B (16B aligned)

__device__ __forceinline__ float gelu_f(float x) {
    return 0.5f * x * (1.0f + erff(x * 0.70710678118654752f));
}

__global__ __launch_bounds__(256) void lno_scan(
    const float* __restrict__ phys,   const float* __restrict__ latents,
    const float* __restrict__ pos_emb,const float* __restrict__ tokW,
    const float* __restrict__ tokb,   const float* __restrict__ physW1,
    const float* __restrict__ physb1, const float* __restrict__ physW2,
    const float* __restrict__ physb2, const float* __restrict__ tn_g,
    const float* __restrict__ tn_b,   const float* __restrict__ tiW,
    const float* __restrict__ tib,    const float* __restrict__ toW,
    const float* __restrict__ tob,    const float* __restrict__ cn_g,
    const float* __restrict__ cn_b,   const float* __restrict__ ciW,
    const float* __restrict__ cib,    const float* __restrict__ coW,
    const float* __restrict__ cob,    const float* __restrict__ hn_g,
    const float* __restrict__ hn_b,   const float* __restrict__ headW,
    const float* __restrict__ headb,  float* __restrict__ out)
{
    __shared__ __align__(16) float tokens[LD][WP];
    __shared__ __align__(16) float ybuf[LD][WP];
    __shared__ __align__(16) float scratch[TH * WP];  // union: hbuf[64][68] / h2buf[32][132] (4352 >= 4224)
    __shared__ float m_s[LD], r_s[LD];
    __shared__ float pvec[W], h1vec[W];
    __shared__ float cur[LD];

    auto hbuf  = (float(*)[WP])scratch;
    auto h2buf = (float(*)[CHP])scratch;

    const int tid  = threadIdx.x;
    const int lane = tid & 63;
    const int wv   = tid >> 6;
    const int b    = blockIdx.x;

    const int th0 = __builtin_amdgcn_readfirstlane(wv * 16);  // token mm1: th block
    const int ld0 = __builtin_amdgcn_readfirstlane(wv * 8);   // mm2 / chan: ld block

    // ---- hoisted per-lane weights (constant across all 256 steps) ----
    const float tokw_r = tokW[lane];
    const float tokb_r = tokb[lane];
    float pe_r[8];
#pragma unroll
    for (int rr = 0; rr < 8; ++rr) pe_r[rr] = pos_emb[(ld0 + rr) * W + lane];

    float tng_r[NL], tnb_r[NL], cng_r[NL], cnb_r[NL], cob_r[NL], cib0_r[NL], cib1_r[NL];
#pragma unroll
    for (int i = 0; i < NL; ++i) {
        tng_r[i]  = tn_g[i * W + lane];
        tnb_r[i]  = tn_b[i * W + lane];
        cng_r[i]  = cn_g[i * W + lane];
        cnb_r[i]  = cn_b[i * W + lane];
        cob_r[i]  = cob[i * W + lane];
        cib0_r[i] = cib[i * CH + lane];
        cib1_r[i] = cib[i * CH + 64 + lane];
    }
    float w1_r[8];
#pragma unroll
    for (int k = 0; k < 8; ++k) w1_r[k] = physW1[k * W + lane];
    const float b1_r = physb1[lane];
    const float b2_r = physb2[lane];

    // head hoists: this thread covers w = sw..sw+7 of row sld
    const int sld = tid >> 3;
    const int sw  = (tid & 7) * 8;
    float gh_r[8];
    float bh = 0.f;
#pragma unroll
    for (int k = 0; k < 8; ++k) {
        const float hw = headW[sw + k];
        gh_r[k] = hn_g[sw + k] * hw;
        bh = fmaf(hn_b[sw + k], hw, bh);
    }
    bh += __shfl_xor(bh, 1, 64);
    bh += __shfl_xor(bh, 2, 64);
    bh += __shfl_xor(bh, 4, 64);
    bh += headb[0];

    if (tid < LD) cur[tid] = latents[b * LD + tid];
    __syncthreads();

    // per-row LN stats of tokens -> m_s[], r_s[]
    auto stats = [&]() {
        const float4 a = *(const float4*)&tokens[sld][sw];
        const float4 c = *(const float4*)&tokens[sld][sw + 4];
        float s = ((a.x + a.y) + (a.z + a.w)) + ((c.x + c.y) + (c.z + c.w));
        float q = a.x * a.x;
        q = fmaf(a.y, a.y, q); q = fmaf(a.z, a.z, q); q = fmaf(a.w, a.w, q);
        q = fmaf(c.x, c.x, q); q = fmaf(c.y, c.y, q); q = fmaf(c.z, c.z, q); q = fmaf(c.w, c.w, q);
        s += __shfl_xor(s, 1, 64); q += __shfl_xor(q, 1, 64);
        s += __shfl_xor(s, 2, 64); q += __shfl_xor(q, 2, 64);
        s += __shfl_xor(s, 4, 64); q += __shfl_xor(q, 4, 64);
        if ((tid & 7) == 0) {
            const float mean = s * 0.015625f;
            const float var  = fmaf(-mean, mean, q * 0.015625f);
            m_s[sld] = mean;
            r_s[sld] = rsqrtf(var + 1e-5f);
        }
    };

#pragma unroll 1
    for (int t = 0; t < Tt; ++t) {
        // ---- phys MLP: p[w] (wave 0 only; tiny: 8+64 MACs per lane) ----
        if (tid < 64) {
            const float* pt = phys + ((size_t)b * Tt + t) * PD;
            float a = b1_r;
#pragma unroll
            for (int k = 0; k < PD; ++k) a = fmaf(pt[k], w1_r[k], a);
            h1vec[lane] = gelu_f(a);
        }
        __syncthreads();
        if (tid < 64) {
            float a = b2_r;
#pragma unroll 8
            for (int k = 0; k < W; ++k) a = fmaf(h1vec[k], physW2[k * W + lane], a);
            pvec[lane] = a;
        }
        __syncthreads();

        // ---- token init: tokens = cur*tokW + tokb + p + pos_emb ----
        {
            const float pv = pvec[lane];
#pragma unroll
            for (int rr = 0; rr < 8; ++rr) {
                const int ld = ld0 + rr;
                tokens[ld][lane] = fmaf(cur[ld], tokw_r, tokb_r + pv + pe_r[rr]);
            }
        }
        __syncthreads();

#pragma unroll
        for (int il = 0; il < NL; ++il) {
            // ======== token mixing ========
            stats();
            __syncthreads();
#pragma unroll
            for (int rr = 0; rr < 8; ++rr) {
                const int ld = ld0 + rr;
                ybuf[ld][lane] = fmaf((tokens[ld][lane] - m_s[ld]) * r_s[ld], tng_r[il], tnb_r[il]);
            }
            __syncthreads();
            {   // mm1: hidden[th][w] = gelu(sum_ld y[ld][w]*tiW[ld][th] + tib[th])
                float acc[16];
                const float* tb = tib + il * TH + th0;
#pragma unroll
                for (int j = 0; j < 16; ++j) acc[j] = tb[j];
                const float* twb = tiW + il * LD * TH + th0;
#pragma unroll 4
                for (int ld = 0; ld < LD; ++ld) {
                    const float yv = ybuf[ld][lane];
                    const float* tw = twb + ld * TH;
#pragma unroll
                    for (int j = 0; j < 16; ++j) acc[j] = fmaf(yv, tw[j], acc[j]);
                }
#pragma unroll
                for (int j = 0; j < 16; ++j) hbuf[th0 + j][lane] = gelu_f(acc[j]);
            }
            __syncthreads();
            {   // mm2: tokens[ld][w] += sum_th hidden[th][w]*toW[th][ld] + tob[ld]
                float acc[8] = {0.f, 0.f, 0.f, 0.f, 0.f, 0.f, 0.f, 0.f};
                const float* twb = toW + il * TH * LD + ld0;
#pragma unroll 4
                for (int th = 0; th < TH; ++th) {
                    const float hv = hbuf[th][lane];
                    const float* tw = twb + th * LD;
#pragma unroll
                    for (int j = 0; j < 8; ++j) acc[j] = fmaf(hv, tw[j], acc[j]);
                }
                const float* tob_p = tob + il * LD + ld0;
#pragma unroll
                for (int j = 0; j < 8; ++j) tokens[ld0 + j][lane] += acc[j] + tob_p[j];
            }
            __syncthreads();

            // ======== channel mixing ========
            stats();
            __syncthreads();
#pragma unroll
            for (int rr = 0; rr < 8; ++rr) {
                const int ld = ld0 + rr;
                ybuf[ld][lane] = fmaf((tokens[ld][lane] - m_s[ld]) * r_s[ld], cng_r[il], cnb_r[il]);
            }
            __syncthreads();
            {   // mm1: h2[ld][ch] = gelu(sum_w y[ld][w]*ciW[w][ch] + cib[ch]), ch in {lane, lane+64}
                float acc0[8] = {0.f, 0.f, 0.f, 0.f, 0.f, 0.f, 0.f, 0.f};
                float acc1[8] = {0.f, 0.f, 0.f, 0.f, 0.f, 0.f, 0.f, 0.f};
                const float* cwb = ciW + il * W * CH;
#pragma unroll 2
                for (int w4 = 0; w4 < W; w4 += 4) {
                    float c0[4], c1[4];
#pragma unroll
                    for (int k = 0; k < 4; ++k) {
                        c0[k] = cwb[(w4 + k) * CH + lane];
                        c1[k] = cwb[(w4 + k) * CH + 64 + lane];
                    }
#pragma unroll
                    for (int j = 0; j < 8; ++j) {
                        const float4 y4 = *(const float4*)&ybuf[ld0 + j][w4];
                        acc0[j] += y4.x * c0[0] + y4.y * c0[1] + y4.z * c0[2] + y4.w * c0[3];
                        acc1[j] += y4.x * c1[0] + y4.y * c1[1] + y4.z * c1[2] + y4.w * c1[3];
                    }
                }
#pragma unroll
                for (int j = 0; j < 8; ++j) {
                    h2buf[ld0 + j][lane]      = gelu_f(acc0[j] + cib0_r[il]);
                    h2buf[ld0 + j][lane + 64] = gelu_f(acc1[j] + cib1_r[il]);
                }
            }
            __syncthreads();
            {   // mm2: tokens[ld][w] += sum_ch h2[ld][ch]*coW[ch][w] + cob[w]
                float acc[8] = {0.f, 0.f, 0.f, 0.f, 0.f, 0.f, 0.f, 0.f};
                const float* cwb = coW + il * CH * W;
#pragma unroll 2
                for (int c4 = 0; c4 < CH; c4 += 4) {
                    float c0[4];
#pragma unroll
                    for (int k = 0; k < 4; ++k) c0[k] = cwb[(c4 + k) * W + lane];
#pragma unroll
                    for (int j = 0; j < 8; ++j) {
                        const float4 h4 = *(const float4*)&h2buf[ld0 + j][c4];
                        acc[j] += h4.x * c0[0] + h4.y * c0[1] + h4.z * c0[2] + h4.w * c0[3];
                    }
                }
#pragma unroll
                for (int j = 0; j < 8; ++j) tokens[ld0 + j][lane] += acc[j] + cob_r[il];
            }
            __syncthreads();
        }

        // ---- head: delta[ld] = LN(tokens; hn) @ headW + headb ----
        stats();
        __syncthreads();
        {
            const float mean = m_s[sld];
            const float4 a = *(const float4*)&tokens[sld][sw];
            const float4 c = *(const float4*)&tokens[sld][sw + 4];
            float lin = (a.x - mean) * gh_r[0];
            lin = fmaf(a.y - mean, gh_r[1], lin);
            lin = fmaf(a.z - mean, gh_r[2], lin);
            lin = fmaf(a.w - mean, gh_r[3], lin);
            lin = fmaf(c.x - mean, gh_r[4], lin);
            lin = fmaf(c.y - mean, gh_r[5], lin);
            lin = fmaf(c.z - mean, gh_r[6], lin);
            lin = fmaf(c.w - mean, gh_r[7], lin);
            lin += __shfl_xor(lin, 1, 64);
            lin += __shfl_xor(lin, 2, 64);
            lin += __shfl_xor(lin, 4, 64);
            if ((tid & 7) == 0) {
                float nv = cur[sld] + fmaf(r_s[sld], lin, bh);
                nv = fminf(fmaxf(nv, 0.f), 1.f);
                cur[sld] = nv;
                out[((size_t)b * Tt + t) * LD + sld] = nv;
            }
        }
        __syncthreads();
    }
}
}  // namespace

extern "C" void kernel_launch(void* const* d_in, const int* in_sizes, int n_in,
                              void* d_out, int out_size, void* d_ws, size_t ws_size,
                              hipStream_t stream) {
    (void)in_sizes; (void)n_in; (void)d_ws; (void)ws_size; (void)out_size;
    const float* phys    = (const float*)d_in[0];
    const float* latents = (const float*)d_in[1];
    const float* pos_emb = (const float*)d_in[2];
    const float* tokW    = (const float*)d_in[3];
    const float* tokb    = (const float*)d_in[4];
    const float* physW1  = (const float*)d_in[5];
    const float* physb1  = (const float*)d_in[6];
    const float* physW2  = (const float*)d_in[7];
    const float* physb2  = (const float*)d_in[8];
    const float* tn_g    = (const float*)d_in[9];
    const float* tn_b    = (const float*)d_in[10];
    const float* tiW     = (const float*)d_in[11];
    const float* tib     = (const float*)d_in[12];
    const float* toW     = (const float*)d_in[13];
    const float* tob     = (const float*)d_in[14];
    const float* cn_g    = (const float*)d_in[15];
    const float* cn_b    = (const float*)d_in[16];
    const float* ciW     = (const float*)d_in[17];
    const float* cib     = (const float*)d_in[18];
    const float* coW     = (const float*)d_in[19];
    const float* cob     = (const float*)d_in[20];
    const float* hn_g    = (const float*)d_in[21];
    const float* hn_b    = (const float*)d_in[22];
    const float* headW   = (const float*)d_in[23];
    const float* headb   = (const float*)d_in[24];

    lno_scan<<<dim3(Bb), dim3(256), 0, stream>>>(
        phys, latents, pos_emb, tokW, tokb, physW1, physb1, physW2, physb2,
        tn_g, tn_b, tiW, tib, toW, tob, cn_g, cn_b, ciW, cib, coW, cob,
        hn_g, hn_b, headW, headb, (float*)d_out);
}

// Round 2
// 25248.195 us; speedup vs baseline: 2.4680x; 2.4680x over previous
//
#include <hip/hip_runtime.h>
#include <hip/hip_bf16.h>
#include <math.h>

// LatentNeuralOperator: scan over T=256, one 256-thread block per batch elem.
// Round 2: all 4 matmuls on bf16 MFMA (16x16x32), state/LN/GELU/residual fp32.
// Weights pre-fragmented into d_ws by lno_prep (runs every launch).
//
// Matmul views (per block, per layer):
//   mm1: C1[th64][w64]  = A(tiW^T)[th][ld32] @ B(y)[ld][w]       K=32
//   mm2: C2[ld32][w64]  = A(toW^T)[ld][th64] @ B(gelu C1)[th][w] K=64
//   mm3: C3T[ch128][ld32] = A(ciW^T)[ch][w64] @ B(y2^T)[w][ld]   K=64  (transposed!)
//   mm4: C4[ld32][w64]  = A(gelu C3T)^T[ld][ch128] @ B(coW)[ch][w] K=128
// Fragment layouts (gfx950, verified m89/m91): A[m=lane&15][k=(lane>>4)*8+j],
// B[k=(lane>>4)*8+j][n=lane&15], C col=lane&15, row=(lane>>4)*4+reg.

namespace {
constexpr int Bb = 2048, Tt = 256, LD = 32, PD = 8, W = 64, NL = 3, TH = 64, CH = 128;
constexpr int WP = W + 4;  // tokens row stride (fp32)

// ws offsets (bytes, all 16B aligned)
constexpr int OFF_TIW = 0;        // 3*4*64*8 shorts        = 12288 B
constexpr int OFF_TOW = 12288;    // 3*2*2*64*8 shorts      = 12288 B
constexpr int OFF_CIW = 24576;    // 3*8*2*64*8 shorts      = 49152 B
constexpr int OFF_COW = 73728;    // 3*4*4*64*8 shorts      = 49152 B
constexpr int OFF_TIB = 122880;   // 3*4*64*4 floats        = 12288 B
constexpr int OFF_TOB = 135168;   // 3*2*64*4 floats        = 6144 B
constexpr int OFF_CIB = 141312;   // 3*8*64*4 floats        = 24576 B

typedef float  f32x4  __attribute__((ext_vector_type(4)));
typedef short  bf16x8 __attribute__((ext_vector_type(8)));
typedef short  bf16x4 __attribute__((ext_vector_type(4)));

#define MFMA16(a, b, c) __builtin_amdgcn_mfma_f32_16x16x32_bf16((a), (b), (c), 0, 0, 0)

__device__ __forceinline__ short f2bf(float x) {
    return __builtin_bit_cast(short, __float2bfloat16(x));
}
__device__ __forceinline__ float gelu_f(float x) {
    return 0.5f * x * (1.0f + erff(x * 0.70710678118654752f));
}

// ---------------- prep: weights -> fragment order in ws ----------------
__global__ void lno_prep(const float* __restrict__ tiW, const float* __restrict__ toW,
                         const float* __restrict__ ciW, const float* __restrict__ coW,
                         const float* __restrict__ tib, const float* __restrict__ tob,
                         const float* __restrict__ cib, char* __restrict__ ws) {
    int id = blockIdx.x * 256 + threadIdx.x;
    // tiWF: [il*4+wv][lane][j]  A1[m=th][k=ld]
    if (id < 6144) {
        int j = id & 7, lane = (id >> 3) & 63, g = id >> 9;
        int il = g >> 2, wv = g & 3;
        int m = wv * 16 + (lane & 15), k = (lane >> 4) * 8 + j;
        ((short*)(ws + OFF_TIW))[id] = f2bf(tiW[il * 2048 + k * 64 + m]);
        return;
    }
    id -= 6144;
    // toWF: [il*4+mt2*2+ks][lane][j]  A2[m=ld][k=th]
    if (id < 6144) {
        int j = id & 7, lane = (id >> 3) & 63, g = id >> 9;
        int il = g >> 2, mt2 = (g >> 1) & 1, ks = g & 1;
        int m = mt2 * 16 + (lane & 15), k = ks * 32 + (lane >> 4) * 8 + j;
        ((short*)(ws + OFF_TOW))[id] = f2bf(toW[il * 2048 + k * 32 + m]);
        return;
    }
    id -= 6144;
    // ciWF: [il*16+mtc*2+ks][lane][j]  A3[m=ch][k=w]
    if (id < 24576) {
        int j = id & 7, lane = (id >> 3) & 63, g = id >> 9;
        int il = g >> 4, mtc = (g >> 1) & 7, ks = g & 1;
        int m = mtc * 16 + (lane & 15), k = ks * 32 + (lane >> 4) * 8 + j;
        ((short*)(ws + OFF_CIW))[id] = f2bf(ciW[il * 8192 + k * 128 + m]);
        return;
    }
    id -= 24576;
    // coWF: [il*16+nt*4+ks][lane][j]  B4[k=ch][n=w]
    if (id < 24576) {
        int j = id & 7, lane = (id >> 3) & 63, g = id >> 9;
        int il = g >> 4, nt = (g >> 2) & 3, ks = g & 3;
        int n = nt * 16 + (lane & 15), k = ks * 32 + (lane >> 4) * 8 + j;
        ((short*)(ws + OFF_COW))[id] = f2bf(coW[il * 8192 + k * 64 + n]);
        return;
    }
    id -= 24576;
    // tibF: [il*4+wv][lane][reg]
    if (id < 3072) {
        int reg = id & 3, lane = (id >> 2) & 63, g = id >> 8;
        int il = g >> 2, wv = g & 3;
        ((float*)(ws + OFF_TIB))[id] = tib[il * 64 + wv * 16 + (lane >> 4) * 4 + reg];
        return;
    }
    id -= 3072;
    // tobF: [il*2+mt2][lane][reg]
    if (id < 1536) {
        int reg = id & 3, lane = (id >> 2) & 63, g = id >> 8;
        int il = g >> 1, mt2 = g & 1;
        ((float*)(ws + OFF_TOB))[id] = tob[il * 32 + mt2 * 16 + (lane >> 4) * 4 + reg];
        return;
    }
    id -= 1536;
    // cibF: [il*8+mtc][lane][reg]
    if (id < 6144) {
        int reg = id & 3, lane = (id >> 2) & 63, g = id >> 8;
        int il = g >> 3, mtc = g & 7;
        ((float*)(ws + OFF_CIB))[id] = cib[il * 128 + mtc * 16 + (lane >> 4) * 4 + reg];
        return;
    }
}

// ---------------- main scan ----------------
__global__ __launch_bounds__(256) void lno_scan(
    const float* __restrict__ phys,   const float* __restrict__ latents,
    const float* __restrict__ pos_emb,const float* __restrict__ tokW,
    const float* __restrict__ tokb,   const float* __restrict__ physW1,
    const float* __restrict__ physb1, const float* __restrict__ physW2,
    const float* __restrict__ physb2, const float* __restrict__ tn_g,
    const float* __restrict__ tn_b,   const float* __restrict__ cn_g,
    const float* __restrict__ cn_b,   const float* __restrict__ hn_g,
    const float* __restrict__ hn_b,   const float* __restrict__ headW,
    const float* __restrict__ headb,  const float* __restrict__ cob,
    const char*  __restrict__ ws,     float* __restrict__ out)
{
    __shared__ __align__(16) float tokens[LD][WP];     // 8704 B, fp32 state
    __shared__ float m_s[LD], r_s[LD];
    __shared__ float pvec[W], h1vec[W], cur[LD];
    __shared__ float cnP[NL][2][W];                    // staged cn_g / cn_b
    __shared__ __align__(16) short yB [4 * 64 * 8];    // B1 frags of y      4 KB
    __shared__ __align__(16) short y2B[4 * 64 * 8];    // B3 frags of y2^T   4 KB
    __shared__ __align__(16) short hB [8 * 64 * 8];    // B2 frags of hidden 8 KB
    __shared__ __align__(16) short h2A[8 * 64 * 8];    // A4 frags of h2     8 KB

    const short* tiWF = (const short*)(ws + OFF_TIW);
    const short* toWF = (const short*)(ws + OFF_TOW);
    const short* ciWF = (const short*)(ws + OFF_CIW);
    const short* coWF = (const short*)(ws + OFF_COW);
    const float* tibF = (const float*)(ws + OFF_TIB);
    const float* tobF = (const float*)(ws + OFF_TOB);
    const float* cibF = (const float*)(ws + OFF_CIB);

    const int tid  = threadIdx.x;
    const int lane = tid & 63;
    const int wv   = tid >> 6;
    const int b    = blockIdx.x;

    const int ld0 = __builtin_amdgcn_readfirstlane(wv * 8);  // token-init rows

    // ---- hoisted per-lane constants ----
    const float tokw_r = tokW[lane];
    const float tokb_r = tokb[lane];
    float pe_r[8];
#pragma unroll
    for (int rr = 0; rr < 8; ++rr) pe_r[rr] = pos_emb[(ld0 + rr) * W + lane];
    float tng_r[NL], tnb_r[NL], cob_r[NL];
#pragma unroll
    for (int i = 0; i < NL; ++i) {
        tng_r[i] = tn_g[i * W + lane];
        tnb_r[i] = tn_b[i * W + lane];
        cob_r[i] = cob[i * W + wv * 16 + (lane & 15)];   // mm4: nt = wv
    }
    float w1_r[8];
#pragma unroll
    for (int k = 0; k < 8; ++k) w1_r[k] = physW1[k * W + lane];
    const float b1_r = physb1[lane];
    const float b2_r = physb2[lane];

    // head hoists: thread covers w = sw..sw+7 of row sld
    const int sld = tid >> 3;
    const int sw  = (tid & 7) * 8;
    float gh_r[8];
    float bh = 0.f;
#pragma unroll
    for (int k = 0; k < 8; ++k) {
        const float hw = headW[sw + k];
        gh_r[k] = hn_g[sw + k] * hw;
        bh = fmaf(hn_b[sw + k], hw, bh);
    }
    bh += __shfl_xor(bh, 1, 64);
    bh += __shfl_xor(bh, 2, 64);
    bh += __shfl_xor(bh, 4, 64);
    bh += headb[0];

    // stage cn params + cur
    for (int idx = tid; idx < NL * 2 * W; idx += 256) {
        int il = idx >> 7, rem = idx & 127;
        ((float*)cnP)[idx] = (rem < W) ? cn_g[il * W + rem] : cn_b[il * W + rem - W];
    }
    if (tid < LD) cur[tid] = latents[b * LD + tid];
    __syncthreads();

    // per-row LN stats of tokens -> m_s[], r_s[]
    auto stats = [&]() {
        const float4 a = *(const float4*)&tokens[sld][sw];
        const float4 c = *(const float4*)&tokens[sld][sw + 4];
        float s = ((a.x + a.y) + (a.z + a.w)) + ((c.x + c.y) + (c.z + c.w));
        float q = a.x * a.x;
        q = fmaf(a.y, a.y, q); q = fmaf(a.z, a.z, q); q = fmaf(a.w, a.w, q);
        q = fmaf(c.x, c.x, q); q = fmaf(c.y, c.y, q); q = fmaf(c.z, c.z, q); q = fmaf(c.w, c.w, q);
        s += __shfl_xor(s, 1, 64); q += __shfl_xor(q, 1, 64);
        s += __shfl_xor(s, 2, 64); q += __shfl_xor(q, 2, 64);
        s += __shfl_xor(s, 4, 64); q += __shfl_xor(q, 4, 64);
        if ((tid & 7) == 0) {
            const float mean = s * 0.015625f;
            const float var  = fmaf(-mean, mean, q * 0.015625f);
            m_s[sld] = mean;
            r_s[sld] = rsqrtf(var + 1e-5f);
        }
    };

#pragma unroll 1
    for (int t = 0; t < Tt; ++t) {
        // ---- phys MLP (wave 0) ----
        if (tid < 64) {
            const float* pt = phys + ((size_t)b * Tt + t) * PD;
            float a = b1_r;
#pragma unroll
            for (int k = 0; k < PD; ++k) a = fmaf(pt[k], w1_r[k], a);
            h1vec[lane] = gelu_f(a);
        }
        __syncthreads();
        if (tid < 64) {
            float a = b2_r;
#pragma unroll 8
            for (int k = 0; k < W; ++k) a = fmaf(h1vec[k], physW2[k * W + lane], a);
            pvec[lane] = a;
        }
        __syncthreads();

        // ---- token init ----
        {
            const float pv = pvec[lane];
#pragma unroll
            for (int rr = 0; rr < 8; ++rr) {
                const int ld = ld0 + rr;
                tokens[ld][lane] = fmaf(cur[ld], tokw_r, tokb_r + pv + pe_r[rr]);
            }
        }
        __syncthreads();

#pragma unroll
        for (int il = 0; il < NL; ++il) {
            // ======== token mixing ========
            stats();
            __syncthreads();
            {   // LN columns -> yB (thread: col=lane, rows wv*8..wv*8+7)
                bf16x8 v;
#pragma unroll
                for (int i = 0; i < 8; ++i) {
                    const int r = wv * 8 + i;
                    const float x = tokens[r][lane];
                    v[i] = f2bf(fmaf((x - m_s[r]) * r_s[r], tng_r[il], tnb_r[il]));
                }
                const int nt = lane >> 4;
                const int laneB = (wv << 4) | (lane & 15);
                *(bf16x8*)&yB[(nt * 64 + laneB) * 8] = v;
            }
            __syncthreads();
            {   // mm1 + gelu -> hB
                const bf16x8 a = *(const bf16x8*)(tiWF + ((il * 4 + wv) * 64 + lane) * 8);
                const f32x4 ci = *(const f32x4*)(tibF + ((il * 4 + wv) * 64 + lane) * 4);
                const int ks = wv >> 1;
                const int lgrp = (wv * 2 + ((lane >> 4) >> 1)) & 3;
                const int jb = ((lane >> 4) & 1) * 4;
                const int laneB = lgrp * 16 + (lane & 15);
#pragma unroll
                for (int nt = 0; nt < 4; ++nt) {
                    const bf16x8 bf = *(const bf16x8*)&yB[(nt * 64 + lane) * 8];
                    f32x4 acc = MFMA16(a, bf, ci);
                    bf16x4 g;
#pragma unroll
                    for (int r = 0; r < 4; ++r) g[r] = f2bf(gelu_f(acc[r]));
                    *(bf16x4*)&hB[((ks * 4 + nt) * 64 + laneB) * 8 + jb] = g;
                }
            }
            __syncthreads();
            {   // mm2 + residual
                const int mt2 = wv & 1, ntb = (wv >> 1) * 2;
                const bf16x8 a0 = *(const bf16x8*)(toWF + ((il * 4 + mt2 * 2 + 0) * 64 + lane) * 8);
                const bf16x8 a1 = *(const bf16x8*)(toWF + ((il * 4 + mt2 * 2 + 1) * 64 + lane) * 8);
                const f32x4 ci = *(const f32x4*)(tobF + ((il * 2 + mt2) * 64 + lane) * 4);
#pragma unroll
                for (int q = 0; q < 2; ++q) {
                    const int nt2 = ntb + q;
                    const bf16x8 b0 = *(const bf16x8*)&hB[((0 * 4 + nt2) * 64 + lane) * 8];
                    const bf16x8 b1 = *(const bf16x8*)&hB[((1 * 4 + nt2) * 64 + lane) * 8];
                    f32x4 acc = MFMA16(a0, b0, ci);
                    acc = MFMA16(a1, b1, acc);
                    const int w = nt2 * 16 + (lane & 15);
                    const int ldb = mt2 * 16 + (lane >> 4) * 4;
#pragma unroll
                    for (int r = 0; r < 4; ++r) tokens[ldb + r][w] += acc[r];
                }
            }
            __syncthreads();

            // ======== channel mixing ========
            stats();
            __syncthreads();
            {   // LN rows -> y2B (thread: sld, sw)
                const float m = m_s[sld], rv = r_s[sld];
                const float* cg = &cnP[il][0][sw];
                const float* cb = &cnP[il][1][sw];
                const float4 t0 = *(const float4*)&tokens[sld][sw];
                const float4 t1 = *(const float4*)&tokens[sld][sw + 4];
                bf16x8 v;
                v[0] = f2bf(fmaf((t0.x - m) * rv, cg[0], cb[0]));
                v[1] = f2bf(fmaf((t0.y - m) * rv, cg[1], cb[1]));
                v[2] = f2bf(fmaf((t0.z - m) * rv, cg[2], cb[2]));
                v[3] = f2bf(fmaf((t0.w - m) * rv, cg[3], cb[3]));
                v[4] = f2bf(fmaf((t1.x - m) * rv, cg[4], cb[4]));
                v[5] = f2bf(fmaf((t1.y - m) * rv, cg[5], cb[5]));
                v[6] = f2bf(fmaf((t1.z - m) * rv, cg[6], cb[6]));
                v[7] = f2bf(fmaf((t1.w - m) * rv, cg[7], cb[7]));
                const int nt = sld >> 4, ks = sw >> 5;
                const int lane2 = ((sw >> 3) & 3) * 16 + (sld & 15);
                *(bf16x8*)&y2B[((nt * 2 + ks) * 64 + lane2) * 8] = v;
            }
            __syncthreads();
            {   // mm3 (transposed) + gelu -> h2A
                bf16x8 aw[2][2];
                f32x4 ci[2];
#pragma unroll
                for (int mq = 0; mq < 2; ++mq) {
                    const int mtc = wv * 2 + mq;
#pragma unroll
                    for (int ks = 0; ks < 2; ++ks)
                        aw[mq][ks] = *(const bf16x8*)(ciWF + ((il * 16 + mtc * 2 + ks) * 64 + lane) * 8);
                    ci[mq] = *(const f32x4*)(cibF + ((il * 8 + mtc) * 64 + lane) * 4);
                }
#pragma unroll
                for (int mq = 0; mq < 2; ++mq) {
                    const int mtc = wv * 2 + mq;
                    const int lgrp = (mtc * 2 + ((lane >> 4) >> 1)) & 3;  // (ch>>3)&3
                    const int jb = ((lane >> 4) & 1) * 4;                 // ch&7 base
                    const int laneh = lgrp * 16 + (lane & 15);
#pragma unroll
                    for (int nt = 0; nt < 2; ++nt) {
                        const bf16x8 b0 = *(const bf16x8*)&y2B[((nt * 2 + 0) * 64 + lane) * 8];
                        const bf16x8 b1 = *(const bf16x8*)&y2B[((nt * 2 + 1) * 64 + lane) * 8];
                        f32x4 acc = MFMA16(aw[mq][0], b0, ci[mq]);
                        acc = MFMA16(aw[mq][1], b1, acc);
                        bf16x4 g;
#pragma unroll
                        for (int r = 0; r < 4; ++r) g[r] = f2bf(gelu_f(acc[r]));
                        // ks4 = ch>>5 = wv
                        *(bf16x4*)&h2A[((nt * 4 + wv) * 64 + laneh) * 8 + jb] = g;
                    }
                }
            }
            __syncthreads();
            {   // mm4 + residual (+cob)
                bf16x8 bw[4];
#pragma unroll
                for (int ks = 0; ks < 4; ++ks)
                    bw[ks] = *(const bf16x8*)(coWF + ((il * 16 + wv * 4 + ks) * 64 + lane) * 8);
                const float cv = cob_r[il];
#pragma unroll
                for (int mt = 0; mt < 2; ++mt) {
                    f32x4 acc = {cv, cv, cv, cv};
#pragma unroll
                    for (int ks = 0; ks < 4; ++ks) {
                        const bf16x8 af = *(const bf16x8*)&h2A[((mt * 4 + ks) * 64 + lane) * 8];
                        acc = MFMA16(af, bw[ks], acc);
                    }
                    const int w = wv * 16 + (lane & 15);
                    const int ldb = mt * 16 + (lane >> 4) * 4;
#pragma unroll
                    for (int r = 0; r < 4; ++r) tokens[ldb + r][w] += acc[r];
                }
            }
            __syncthreads();
        }

        // ---- head ----
        stats();
        __syncthreads();
        {
            const float mean = m_s[sld];
            const float4 a = *(const float4*)&tokens[sld][sw];
            const float4 c = *(const float4*)&tokens[sld][sw + 4];
            float lin = (a.x - mean) * gh_r[0];
            lin = fmaf(a.y - mean, gh_r[1], lin);
            lin = fmaf(a.z - mean, gh_r[2], lin);
            lin = fmaf(a.w - mean, gh_r[3], lin);
            lin = fmaf(c.x - mean, gh_r[4], lin);
            lin = fmaf(c.y - mean, gh_r[5], lin);
            lin = fmaf(c.z - mean, gh_r[6], lin);
            lin = fmaf(c.w - mean, gh_r[7], lin);
            lin += __shfl_xor(lin, 1, 64);
            lin += __shfl_xor(lin, 2, 64);
            lin += __shfl_xor(lin, 4, 64);
            if ((tid & 7) == 0) {
                float nv = cur[sld] + fmaf(r_s[sld], lin, bh);
                nv = fminf(fmaxf(nv, 0.f), 1.f);
                cur[sld] = nv;
                out[((size_t)b * Tt + t) * LD + sld] = nv;
            }
        }
        __syncthreads();
    }
}
}  // namespace

extern "C" void kernel_launch(void* const* d_in, const int* in_sizes, int n_in,
                              void* d_out, int out_size, void* d_ws, size_t ws_size,
                              hipStream_t stream) {
    (void)in_sizes; (void)n_in; (void)ws_size; (void)out_size;
    const float* phys    = (const float*)d_in[0];
    const float* latents = (const float*)d_in[1];
    const float* pos_emb = (const float*)d_in[2];
    const float* tokW    = (const float*)d_in[3];
    const float* tokb    = (const float*)d_in[4];
    const float* physW1  = (const float*)d_in[5];
    const float* physb1  = (const float*)d_in[6];
    const float* physW2  = (const float*)d_in[7];
    const float* physb2  = (const float*)d_in[8];
    const float* tn_g    = (const float*)d_in[9];
    const float* tn_b    = (const float*)d_in[10];
    const float* tiW     = (const float*)d_in[11];
    const float* tib     = (const float*)d_in[12];
    const float* toW     = (const float*)d_in[13];
    const float* tob     = (const float*)d_in[14];
    const float* cn_g    = (const float*)d_in[15];
    const float* cn_b    = (const float*)d_in[16];
    const float* ciW     = (const float*)d_in[17];
    const float* cib     = (const float*)d_in[18];
    const float* coW     = (const float*)d_in[19];
    const float* cob     = (const float*)d_in[20];
    const float* hn_g    = (const float*)d_in[21];
    const float* hn_b    = (const float*)d_in[22];
    const float* headW   = (const float*)d_in[23];
    const float* headb   = (const float*)d_in[24];

    lno_prep<<<dim3(282), dim3(256), 0, stream>>>(tiW, toW, ciW, coW, tib, tob, cib,
                                                  (char*)d_ws);
    lno_scan<<<dim3(Bb), dim3(256), 0, stream>>>(
        phys, latents, pos_emb, tokW, tokb, physW1, physb1, physW2, physb2,
        tn_g, tn_b, cn_g, cn_b, hn_g, hn_b, headW, headb, cob,
        (const char*)d_ws, (float*)d_out);
}

// Round 3
// 7978.888 us; speedup vs baseline: 7.8096x; 3.1644x over previous
//
#include <hip/hip_runtime.h>
#include <hip/hip_bf16.h>
#include <math.h>

// Round 3: one WAVE per batch element (grid 512 x 256thr, 4 waves/block).
// Token state [32][64] fp32 lives in registers in MFMA C-layout:
//   lane (q=lane>>4, c=lane&15) holds tok[mt][nt][r] = tokens[mt*16+q*4+r][nt*16+c]
// LN stats = in-register DPP row_ror reductions. Fragment repacks = per-wave
// LDS round trips (lgkmcnt only, NO __syncthreads). The only barriers (2/layer)
// guard a block-shared LDS weight cache (ciW/coW staged via global_load_lds).
// mm2/mm4 accumulate straight into the token-state registers.
//
// Fragment layouts (gfx950, verified m89/m91 + round 2):
//   A[m=lane&15][k=(lane>>4)*8+j], B[k=(lane>>4)*8+j][n=lane&15],
//   C: col=lane&15, row=(lane>>4)*4+reg.

namespace {
constexpr int Tt = 256, NL = 3;

typedef float  f32x4  __attribute__((ext_vector_type(4)));
typedef short  bf16x8 __attribute__((ext_vector_type(8)));
typedef short  bf16x4 __attribute__((ext_vector_type(4)));

#define MFMA16(a, b, c) __builtin_amdgcn_mfma_f32_16x16x32_bf16((a), (b), (c), 0, 0, 0)

__device__ __forceinline__ short f2bf(float x) {
    return __builtin_bit_cast(short, __float2bfloat16(x));
}
__device__ __forceinline__ float bf2f(short s) {
    return __builtin_bit_cast(float, ((int)(unsigned short)s) << 16);
}
// tanh-form GELU via exp2 (max err ~1e-4, << bf16 rounding already present)
__device__ __forceinline__ float gelu_f(float x) {
    float x2 = x * x;
    float u = x * fmaf(x2, 0.1029434f, 2.3022077f);  // 2*log2(e)*(0.797885 + 0.0446715*... folded)
    float e = __builtin_amdgcn_exp2f(u);
    float r = __builtin_amdgcn_rcpf(e + 1.0f);
    return x - x * r;  // x*e/(e+1)
}
// sum across the 16-lane DPP row (all lanes get the total)
__device__ __forceinline__ float rowsum16(float x) {
    x += __builtin_bit_cast(float, __builtin_amdgcn_update_dpp(0, __builtin_bit_cast(int, x), 0x121, 0xf, 0xf, false));
    x += __builtin_bit_cast(float, __builtin_amdgcn_update_dpp(0, __builtin_bit_cast(int, x), 0x122, 0xf, 0xf, false));
    x += __builtin_bit_cast(float, __builtin_amdgcn_update_dpp(0, __builtin_bit_cast(int, x), 0x124, 0xf, 0xf, false));
    x += __builtin_bit_cast(float, __builtin_amdgcn_update_dpp(0, __builtin_bit_cast(int, x), 0x128, 0xf, 0xf, false));
    return x;
}

// ws layout (shorts): tiWF[0,6144) toWF[6144,12288) ciWF[12288,36864)
//                     coWF[36864,61440) W2T[61440,65536)
__global__ void lno_prep(const float* __restrict__ tiW, const float* __restrict__ toW,
                         const float* __restrict__ ciW, const float* __restrict__ coW,
                         const float* __restrict__ physW2, short* __restrict__ wsf) {
    int id = blockIdx.x * 256 + threadIdx.x;  // 0..65535
    if (id < 6144) {            // A1: m=th, k=ld
        int j = id & 7, lane = (id >> 3) & 63, g = id >> 9;
        int il = g >> 2, u = g & 3;
        int m = u * 16 + (lane & 15), k = (lane >> 4) * 8 + j;
        wsf[id] = f2bf(tiW[il * 2048 + k * 64 + m]);
    } else if (id < 12288) {    // A2: m=ld, k=th
        int t = id - 6144;
        int j = t & 7, lane = (t >> 3) & 63, g = t >> 9;
        int il = g >> 2, mt2 = (g >> 1) & 1, ks = g & 1;
        int m = mt2 * 16 + (lane & 15), k = ks * 32 + (lane >> 4) * 8 + j;
        wsf[id] = f2bf(toW[il * 2048 + k * 32 + m]);
    } else if (id < 36864) {    // A3: m=ch, k=w
        int t = id - 12288;
        int j = t & 7, lane = (t >> 3) & 63, g = t >> 9;
        int il = g >> 4, mtc = (g >> 1) & 7, ks = g & 1;
        int m = mtc * 16 + (lane & 15), k = ks * 32 + (lane >> 4) * 8 + j;
        wsf[id] = f2bf(ciW[il * 8192 + k * 128 + m]);
    } else if (id < 61440) {    // B4: k=ch, n=w
        int t = id - 36864;
        int j = t & 7, lane = (t >> 3) & 63, g = t >> 9;
        int il = g >> 4, nt = (g >> 2) & 3, ks = g & 3;
        int n = nt * 16 + (lane & 15), k = ks * 32 + (lane >> 4) * 8 + j;
        wsf[id] = f2bf(coW[il * 8192 + k * 64 + n]);
    } else if (id < 65536) {    // W2T[w][k]
        int t = id - 61440;
        int w = t >> 6, k = t & 63;
        wsf[id] = f2bf(physW2[k * 64 + w]);
    }
}

__global__ __launch_bounds__(256, 2) void lno_scan(
    const float* __restrict__ phys,   const float* __restrict__ latents,
    const float* __restrict__ pos_emb,const float* __restrict__ tokW,
    const float* __restrict__ tokb,   const float* __restrict__ physW1,
    const float* __restrict__ physb1, const float* __restrict__ physb2,
    const float* __restrict__ tn_g,   const float* __restrict__ tn_b,
    const float* __restrict__ tib,    const float* __restrict__ tob,
    const float* __restrict__ cn_g,   const float* __restrict__ cn_b,
    const float* __restrict__ cib,    const float* __restrict__ cob,
    const float* __restrict__ hn_g,   const float* __restrict__ hn_b,
    const float* __restrict__ headW,  const float* __restrict__ headb,
    const short* __restrict__ wsf,    float* __restrict__ out)
{
    __shared__ __align__(16) short bufA[4][2048];   // per-wave: yB (B1) then y2B (B3, swizzled)
    __shared__ __align__(16) short bufB[4][2048];   // per-wave: hB halves (B2) then h2A halves (A4)
    __shared__ __align__(16) short wbufC[8192];     // block-shared ciW frags (layer il)
    __shared__ __align__(16) short wbufO[8192];     // block-shared coW frags (layer il)
    __shared__ __align__(16) float biasL[672];      // tib[0,192) tob[192,288) cib[288,672)
    __shared__ __align__(16) float pvh[4][128];     // per-wave phys h1 / p exchange

    const short* tiWF = wsf;
    const short* toWF = wsf + 6144;
    const short* ciWF = wsf + 12288;
    const short* coWF = wsf + 36864;
    const short* W2T  = wsf + 61440;

    const int tid = threadIdx.x, lane = tid & 63, wv = tid >> 6;
    const int q = lane >> 4, c = lane & 15;
    const int b = blockIdx.x * 4 + wv;

    short* yb = bufA[wv];
    short* hb = bufB[wv];

    // ---- stage biases into LDS (once) ----
    for (int i = tid; i < 192; i += 256) biasL[i] = tib[i];
    for (int i = tid; i < 96;  i += 256) biasL[192 + i] = tob[i];
    for (int i = tid; i < 384; i += 256) biasL[288 + i] = cib[i];

    // ---- hoisted per-lane constants ----
    float tokw_r[4], tokb_r[4], gh_r[4];
#pragma unroll
    for (int nt = 0; nt < 4; ++nt) {
        tokw_r[nt] = tokW[nt * 16 + c];
        tokb_r[nt] = tokb[nt * 16 + c];
        gh_r[nt]   = hn_g[nt * 16 + c] * headW[nt * 16 + c];
    }
    float bhp = 0.f;
#pragma unroll
    for (int nt = 0; nt < 4; ++nt) bhp = fmaf(hn_b[nt * 16 + c], headW[nt * 16 + c], bhp);
    const float bh = rowsum16(bhp) + headb[0];

    float pe_r[2][4][4];
#pragma unroll
    for (int mt = 0; mt < 2; ++mt)
#pragma unroll
        for (int nt = 0; nt < 4; ++nt)
#pragma unroll
            for (int r = 0; r < 4; ++r)
                pe_r[mt][nt][r] = pos_emb[(mt * 16 + q * 4 + r) * 64 + nt * 16 + c];

    float w1_r[8];
#pragma unroll
    for (int k = 0; k < 8; ++k) w1_r[k] = physW1[k * 64 + lane];
    const float b1_r = physb1[lane];
    const float b2_r = physb2[lane];

    f32x4 cur8[2];
#pragma unroll
    for (int mt = 0; mt < 2; ++mt)
        cur8[mt] = *(const f32x4*)(latents + b * 32 + mt * 16 + q * 4);

    f32x4 tok[2][4];

    __syncthreads();  // biasL ready

    auto stats = [&](f32x4 (&mean)[2], f32x4 (&rsig)[2]) {
#pragma unroll
        for (int mt = 0; mt < 2; ++mt)
#pragma unroll
            for (int r = 0; r < 4; ++r) {
                float s = (tok[mt][0][r] + tok[mt][1][r]) + (tok[mt][2][r] + tok[mt][3][r]);
                float qq = tok[mt][0][r] * tok[mt][0][r];
                qq = fmaf(tok[mt][1][r], tok[mt][1][r], qq);
                qq = fmaf(tok[mt][2][r], tok[mt][2][r], qq);
                qq = fmaf(tok[mt][3][r], tok[mt][3][r], qq);
                s = rowsum16(s); qq = rowsum16(qq);
                float m = s * 0.015625f;
                float v = fmaf(-m, m, qq * 0.015625f);
                mean[mt][r] = m;
                rsig[mt][r] = __builtin_amdgcn_rsqf(v + 1e-5f);
            }
    };

#pragma unroll 1
    for (int t = 0; t < Tt; ++t) {
        // ======== phys MLP (per wave, lane = w) ========
        {
            const float* pt = phys + ((size_t)b * Tt + t) * 8;
            float4 px0 = *(const float4*)pt, px1 = *(const float4*)(pt + 4);
            float a = b1_r;
            a = fmaf(px0.x, w1_r[0], a); a = fmaf(px0.y, w1_r[1], a);
            a = fmaf(px0.z, w1_r[2], a); a = fmaf(px0.w, w1_r[3], a);
            a = fmaf(px1.x, w1_r[4], a); a = fmaf(px1.y, w1_r[5], a);
            a = fmaf(px1.z, w1_r[6], a); a = fmaf(px1.w, w1_r[7], a);
            pvh[wv][lane] = gelu_f(a);
        }
        float pnt[4];
        {
            float acc = b2_r;
            const bf16x8* w2p = (const bf16x8*)(W2T + lane * 64);
            const f32x4* h4 = (const f32x4*)&pvh[wv][0];
#pragma unroll
            for (int kk = 0; kk < 8; ++kk) {
                bf16x8 w8 = w2p[kk];
                f32x4 ha = h4[kk * 2], hbv = h4[kk * 2 + 1];
                acc = fmaf(ha[0], bf2f(w8[0]), acc); acc = fmaf(ha[1], bf2f(w8[1]), acc);
                acc = fmaf(ha[2], bf2f(w8[2]), acc); acc = fmaf(ha[3], bf2f(w8[3]), acc);
                acc = fmaf(hbv[0], bf2f(w8[4]), acc); acc = fmaf(hbv[1], bf2f(w8[5]), acc);
                acc = fmaf(hbv[2], bf2f(w8[6]), acc); acc = fmaf(hbv[3], bf2f(w8[7]), acc);
            }
            pvh[wv][64 + lane] = acc;
#pragma unroll
            for (int nt = 0; nt < 4; ++nt) pnt[nt] = pvh[wv][64 + nt * 16 + c];
        }

        // ======== token init (into C-layout regs) ========
#pragma unroll
        for (int nt = 0; nt < 4; ++nt) {
            const float basep = tokb_r[nt] + pnt[nt];
#pragma unroll
            for (int mt = 0; mt < 2; ++mt)
#pragma unroll
                for (int r = 0; r < 4; ++r)
                    tok[mt][nt][r] = fmaf(cur8[mt][r], tokw_r[nt], basep + pe_r[mt][nt][r]);
        }

#pragma unroll 1
        for (int il = 0; il < NL; ++il) {
            __syncthreads();  // (A) all waves done reading wbufC/wbufO
            {                 // stage ciW(il)->wbufC, coW(il)->wbufO (async DMA)
                const unsigned int* srcC = (const unsigned int*)(ciWF + il * 8192);
                const unsigned int* srcO = (const unsigned int*)(coWF + il * 8192);
#pragma unroll
                for (int i = 0; i < 4; ++i) {
                    const int chunk = i * 4 + wv;
                    __builtin_amdgcn_global_load_lds(srcC + chunk * 256 + lane * 4,
                                                     (unsigned int*)&wbufC[chunk * 512], 16, 0, 0);
                    __builtin_amdgcn_global_load_lds(srcO + chunk * 256 + lane * 4,
                                                     (unsigned int*)&wbufO[chunk * 512], 16, 0, 0);
                }
            }

            // ======== token mixing ========
            f32x4 mean[2], rsig[2];
            stats(mean, rsig);
            float tng[4], tnb[4];
#pragma unroll
            for (int nt = 0; nt < 4; ++nt) {
                tng[nt] = tn_g[il * 64 + nt * 16 + c];
                tnb[nt] = tn_b[il * 64 + nt * 16 + c];
            }
            // LN1 -> yB (B1 frags): row k = mt*16+q*4+r -> slot lane (mt*2+(q>>1))*16+c, j=(q&1)*4+r
#pragma unroll
            for (int mt = 0; mt < 2; ++mt)
#pragma unroll
                for (int nt = 0; nt < 4; ++nt) {
                    bf16x4 v4;
#pragma unroll
                    for (int r = 0; r < 4; ++r)
                        v4[r] = f2bf(fmaf((tok[mt][nt][r] - mean[mt][r]) * rsig[mt][r], tng[nt], tnb[nt]));
                    *(bf16x4*)&yb[(nt * 64 + (mt * 2 + (q >> 1)) * 16 + c) * 8 + (q & 1) * 4] = v4;
                }
            bf16x8 yfrag[4];
#pragma unroll
            for (int nt = 0; nt < 4; ++nt) yfrag[nt] = *(const bf16x8*)&yb[(nt * 64 + lane) * 8];

            // pre-add tob (per-row) into tok; mm2 then accumulates in place
#pragma unroll
            for (int mt = 0; mt < 2; ++mt) {
                const f32x4 tb = *(const f32x4*)&biasL[192 + il * 32 + mt * 16 + q * 4];
#pragma unroll
                for (int nt = 0; nt < 4; ++nt) tok[mt][nt] += tb;
            }
            // mm1 (gelu->hB half) + mm2 (into tok), split by K-half h
#pragma unroll
            for (int h = 0; h < 2; ++h) {
#pragma unroll
                for (int uu = 0; uu < 2; ++uu) {
                    const int u = h * 2 + uu;
                    const bf16x8 a1 = *(const bf16x8*)(tiWF + ((il * 4 + u) * 64 + lane) * 8);
                    const f32x4 bi = *(const f32x4*)&biasL[il * 64 + u * 16 + q * 4];
#pragma unroll
                    for (int nt = 0; nt < 4; ++nt) {
                        f32x4 acc = MFMA16(a1, yfrag[nt], bi);
                        bf16x4 g4;
#pragma unroll
                        for (int r = 0; r < 4; ++r) g4[r] = f2bf(gelu_f(acc[r]));
                        *(bf16x4*)&hb[(nt * 64 + (uu * 2 + (q >> 1)) * 16 + c) * 8 + (q & 1) * 4] = g4;
                    }
                }
                bf16x8 hf[4];
#pragma unroll
                for (int nt = 0; nt < 4; ++nt) hf[nt] = *(const bf16x8*)&hb[(nt * 64 + lane) * 8];
#pragma unroll
                for (int mt = 0; mt < 2; ++mt) {
                    const bf16x8 a2 = *(const bf16x8*)(toWF + ((il * 4 + mt * 2 + h) * 64 + lane) * 8);
#pragma unroll
                    for (int nt = 0; nt < 4; ++nt) tok[mt][nt] = MFMA16(a2, hf[nt], tok[mt][nt]);
                }
            }

            // ======== channel mixing ========
            stats(mean, rsig);
            float cng[4], cnb[4];
#pragma unroll
            for (int nt = 0; nt < 4; ++nt) {
                cng[nt] = cn_g[il * 64 + nt * 16 + c];
                cnb[nt] = cn_b[il * 64 + nt * 16 + c];
            }
            // LN2 -> y2B (B3 frags, swizzled slots; conflict-free b16 scatter)
            // slot': F = mt*2+(nt>>1); lam' = q*2+(c>>3)+16r+8(nt&1); j = c&7
#pragma unroll
            for (int mt = 0; mt < 2; ++mt)
#pragma unroll
                for (int nt = 0; nt < 4; ++nt)
#pragma unroll
                    for (int r = 0; r < 4; ++r) {
                        float v = fmaf((tok[mt][nt][r] - mean[mt][r]) * rsig[mt][r], cng[nt], cnb[nt]);
                        yb[(mt * 2 + (nt >> 1)) * 512 +
                           (q * 2 + (c >> 3) + 16 * r + 8 * (nt & 1)) * 8 + (c & 7)] = f2bf(v);
                    }
            bf16x8 b3[4];
            {
                const int lp = ((c >> 2) * 2 + (q & 1)) + 8 * ((c & 3) * 2 + (q >> 1));
#pragma unroll
                for (int F = 0; F < 4; ++F) b3[F] = *(const bf16x8*)&yb[F * 512 + lp * 8];
            }
            // pre-add cob (per-col) into tok; mm4 accumulates in place
#pragma unroll
            for (int nt = 0; nt < 4; ++nt) {
                const float cv = cob[il * 64 + nt * 16 + c];
#pragma unroll
                for (int mt = 0; mt < 2; ++mt) tok[mt][nt] += cv;
            }

            __syncthreads();  // (B) staged wbufC/wbufO ready (vmcnt drained)

            // mm3 (gelu->h2A half) + mm4 (into tok), split by ch-half hh
#pragma unroll
            for (int hh = 0; hh < 2; ++hh) {
#pragma unroll
                for (int mm = 0; mm < 4; ++mm) {
                    const int mtc = hh * 4 + mm;
                    const bf16x8 a30 = *(const bf16x8*)&wbufC[(mtc * 2 + 0) * 512 + lane * 8];
                    const bf16x8 a31 = *(const bf16x8*)&wbufC[(mtc * 2 + 1) * 512 + lane * 8];
                    const f32x4 bi3 = *(const f32x4*)&biasL[288 + il * 128 + mtc * 16 + q * 4];
#pragma unroll
                    for (int ntl = 0; ntl < 2; ++ntl) {
                        f32x4 acc = MFMA16(a30, b3[ntl * 2 + 0], bi3);
                        acc = MFMA16(a31, b3[ntl * 2 + 1], acc);
                        bf16x4 g4;
#pragma unroll
                        for (int r = 0; r < 4; ++r) g4[r] = f2bf(gelu_f(acc[r]));
                        *(bf16x4*)&hb[((ntl * 2 + ((mtc >> 1) & 1)) * 64 +
                                       ((mtc & 1) * 2 + (q >> 1)) * 16 + c) * 8 + (q & 1) * 4] = g4;
                    }
                }
                bf16x8 a4[2][2];
#pragma unroll
                for (int mt = 0; mt < 2; ++mt)
#pragma unroll
                    for (int kk = 0; kk < 2; ++kk)
                        a4[mt][kk] = *(const bf16x8*)&hb[((mt * 2 + kk) * 64 + lane) * 8];
#pragma unroll
                for (int nt = 0; nt < 4; ++nt) {
                    const bf16x8 b40 = *(const bf16x8*)&wbufO[(nt * 4 + hh * 2 + 0) * 512 + lane * 8];
                    const bf16x8 b41 = *(const bf16x8*)&wbufO[(nt * 4 + hh * 2 + 1) * 512 + lane * 8];
#pragma unroll
                    for (int mt = 0; mt < 2; ++mt) {
                        tok[mt][nt] = MFMA16(a4[mt][0], b40, tok[mt][nt]);
                        tok[mt][nt] = MFMA16(a4[mt][1], b41, tok[mt][nt]);
                    }
                }
            }
        }  // il

        // ======== head ========
        {
            f32x4 mean[2], rsig[2];
            stats(mean, rsig);
#pragma unroll
            for (int mt = 0; mt < 2; ++mt)
#pragma unroll
                for (int r = 0; r < 4; ++r) {
                    float l = (tok[mt][0][r] - mean[mt][r]) * gh_r[0];
                    l = fmaf(tok[mt][1][r] - mean[mt][r], gh_r[1], l);
                    l = fmaf(tok[mt][2][r] - mean[mt][r], gh_r[2], l);
                    l = fmaf(tok[mt][3][r] - mean[mt][r], gh_r[3], l);
                    l = rowsum16(l);
                    float nv = cur8[mt][r] + fmaf(rsig[mt][r], l, bh);
                    nv = fminf(fmaxf(nv, 0.f), 1.f);
                    cur8[mt][r] = nv;
                }
            if (c == 0) {
                float* op = out + ((size_t)b * Tt + t) * 32 + q * 4;
                *(f32x4*)(op) = cur8[0];
                *(f32x4*)(op + 16) = cur8[1];
            }
        }
    }  // t
}
}  // namespace

extern "C" void kernel_launch(void* const* d_in, const int* in_sizes, int n_in,
                              void* d_out, int out_size, void* d_ws, size_t ws_size,
                              hipStream_t stream) {
    (void)in_sizes; (void)n_in; (void)ws_size; (void)out_size;
    const float* phys    = (const float*)d_in[0];
    const float* latents = (const float*)d_in[1];
    const float* pos_emb = (const float*)d_in[2];
    const float* tokW    = (const float*)d_in[3];
    const float* tokb    = (const float*)d_in[4];
    const float* physW1  = (const float*)d_in[5];
    const float* physb1  = (const float*)d_in[6];
    const float* physW2  = (const float*)d_in[7];
    const float* physb2  = (const float*)d_in[8];
    const float* tn_g    = (const float*)d_in[9];
    const float* tn_b    = (const float*)d_in[10];
    const float* tiW     = (const float*)d_in[11];
    const float* tib     = (const float*)d_in[12];
    const float* toW     = (const float*)d_in[13];
    const float* tob     = (const float*)d_in[14];
    const float* cn_g    = (const float*)d_in[15];
    const float* cn_b    = (const float*)d_in[16];
    const float* ciW     = (const float*)d_in[17];
    const float* cib     = (const float*)d_in[18];
    const float* coW     = (const float*)d_in[19];
    const float* cob     = (const float*)d_in[20];
    const float* hn_g    = (const float*)d_in[21];
    const float* hn_b    = (const float*)d_in[22];
    const float* headW   = (const float*)d_in[23];
    const float* headb   = (const float*)d_in[24];

    lno_prep<<<dim3(256), dim3(256), 0, stream>>>(tiW, toW, ciW, coW, physW2, (short*)d_ws);
    lno_scan<<<dim3(512), dim3(256), 0, stream>>>(
        phys, latents, pos_emb, tokW, tokb, physW1, physb1, physb2,
        tn_g, tn_b, tib, tob, cn_g, cn_b, cib, cob, hn_g, hn_b, headW, headb,
        (const short*)d_ws, (float*)d_out);
}